// Round 19
// baseline (267.093 us; speedup 1.0000x reference)
//
#include <hip/hip_runtime.h>
#include <hip/hip_bf16.h>

#define B_ 8
#define C_ 256
#define S_ 4096
#define G_ 32
#define GC_ 8
#define EPS_ 1e-5f

typedef __attribute__((ext_vector_type(4))) float f32x4;
typedef __attribute__((ext_vector_type(8))) short bf16x8;
typedef __attribute__((ext_vector_type(4))) short bf16x4;
typedef __attribute__((ext_vector_type(4))) unsigned int u32x4;
typedef __attribute__((ext_vector_type(2))) unsigned int u32x2;

#define DI __device__ __forceinline__

DI unsigned short f2bf(float f) {
    union { float f; unsigned u; } v; v.f = f;
    unsigned r = v.u + 0x7fffu + ((v.u >> 16) & 1u);
    return (unsigned short)(r >> 16);
}

DI unsigned cvt_pk_bf16(float lo, float hi) {
    unsigned r;
    asm("v_cvt_pk_bf16_f32 %0, %1, %2" : "=v"(r) : "v"(lo), "v"(hi));
    return r;
}

DI unsigned cvt_pk_fp8(float lo, float hi) {  // bits [7:0]=fp8(lo), [15:8]=fp8(hi)
    unsigned r;
    asm("v_cvt_pk_fp8_f32 %0, %1, %2" : "=v"(r) : "v"(lo), "v"(hi));
    return r;
}

DI f32x4 mfma_fp8(u32x2 a, u32x2 b, f32x4 c) {
    union { u32x2 u; long l; } ua, ub;
    ua.u = a; ub.u = b;
    return __builtin_amdgcn_mfma_f32_16x16x32_fp8_fp8(ua.l, ub.l, c, 0, 0, 0);
}

// ---------------- GroupNorm stats: one block per (b, group) ----------------
__global__ __launch_bounds__(256) void k_gn_stats(const float* __restrict__ x,
                                                  float* __restrict__ stats) {
    int bg = blockIdx.x;
    const float4* xp = (const float4*)(x + (size_t)bg * (GC_ * S_));
    float s = 0.f, ss = 0.f;
    for (int i = threadIdx.x; i < GC_ * S_ / 4; i += 256) {
        float4 v = xp[i];
        s  += v.x + v.y + v.z + v.w;
        ss += v.x * v.x + v.y * v.y + v.z * v.z + v.w * v.w;
    }
    #pragma unroll
    for (int off = 32; off; off >>= 1) { s += __shfl_down(s, off); ss += __shfl_down(ss, off); }
    __shared__ float rs[4], rss[4];
    int w = threadIdx.x >> 6;
    if ((threadIdx.x & 63) == 0) { rs[w] = s; rss[w] = ss; }
    __syncthreads();
    if (threadIdx.x == 0) {
        float S1 = rs[0] + rs[1] + rs[2] + rs[3];
        float S2 = rss[0] + rss[1] + rss[2] + rss[3];
        float inv = 1.f / (GC_ * S_);
        float mean = S1 * inv;
        float var = S2 * inv - mean * mean;
        stats[bg * 2] = mean;
        stats[bg * 2 + 1] = rsqrtf(var + EPS_);
    }
}

// ------------- GN apply + transpose: x[B][C][S] -> h_sc[B][S][C] bf16 -------------
__global__ __launch_bounds__(256) void k_gn_apply(const float* __restrict__ x,
                                                  const float* __restrict__ stats,
                                                  const float* __restrict__ gw,
                                                  const float* __restrict__ gb,
                                                  unsigned short* __restrict__ h) {
    int b = blockIdx.x >> 6;
    int s0 = (blockIdx.x & 63) * 64;
    __shared__ unsigned short tile[64 * 256];
    const float* xb = x + (size_t)b * C_ * S_;
    for (int id = threadIdx.x; id < 256 * 16; id += 256) {
        int c = id >> 4, s4 = id & 15;
        float4 v = *(const float4*)(xb + (size_t)c * S_ + s0 + s4 * 4);
        float mean = stats[(b * G_ + (c >> 3)) * 2];
        float rstd = stats[(b * G_ + (c >> 3)) * 2 + 1];
        float ga = gw[c], be = gb[c];
        float vv[4] = {v.x, v.y, v.z, v.w};
        #pragma unroll
        for (int i = 0; i < 4; i++) {
            int srow = s4 * 4 + i;
            unsigned byte = srow * 512u + c * 2u;
            byte ^= ((srow & 7u) << 4);
            *(unsigned short*)((char*)tile + byte) = f2bf((vv[i] - mean) * rstd * ga + be);
        }
    }
    __syncthreads();
    unsigned short* hb = h + (size_t)b * S_ * C_;
    for (int id = threadIdx.x; id < 2048; id += 256) {
        int srow = id >> 5, ck = id & 31;
        unsigned byte = srow * 512u + ck * 16u;
        byte ^= ((srow & 7u) << 4);
        u32x4 v = *(u32x4*)((char*)tile + byte);
        *(u32x4*)(hb + (size_t)(s0 + srow) * C_ + ck * 8) = v;
    }
}

// ---------------- W fp32 -> bf16 pre-pass ----------------
__global__ __launch_bounds__(256) void k_wcvt(const float* __restrict__ wq, const float* __restrict__ wk,
                                              const float* __restrict__ wv, const float* __restrict__ wp,
                                              unsigned short* __restrict__ wbf) {
    int t = blockIdx.x * 256 + threadIdx.x;
    int mat = t >> 13;
    int idx = (t & 8191) * 8;
    const float* src = mat == 0 ? wq : mat == 1 ? wk : mat == 2 ? wv : wp;
    float4 a = *(const float4*)(src + idx);
    float4 c = *(const float4*)(src + idx + 4);
    unsigned short tmp[8] = {f2bf(a.x), f2bf(a.y), f2bf(a.z), f2bf(a.w),
                             f2bf(c.x), f2bf(c.y), f2bf(c.z), f2bf(c.w)};
    *(u32x4*)(wbf + mat * 65536 + idx) = *(u32x4*)tmp;
}

// ---------------- Fused QKV GEMM: Q,K -> fp8 [S][C]; V -> fp8 [C][S] ----------------
__global__ __launch_bounds__(256) void k_qkv(const unsigned short* __restrict__ wbf,
                                             const float* __restrict__ bq,
                                             const float* __restrict__ bk,
                                             const float* __restrict__ bv,
                                             const unsigned short* __restrict__ h,
                                             unsigned char* __restrict__ q8,
                                             unsigned char* __restrict__ k8,
                                             unsigned char* __restrict__ v8) {
    int mode = blockIdx.x >> 9;
    int inner = blockIdx.x & 511;
    int b = inner & 7;
    int rest = inner >> 3;
    int m0 = (rest & 1) * 128;
    int n0 = (rest >> 1) * 128;
    const unsigned short* W = wbf + mode * 65536;
    const float* bias = mode == 0 ? bq : (mode == 1 ? bk : bv);

    __shared__ unsigned short Alds[128 * 64];
    __shared__ unsigned short Blds[128 * 64];
    int tid = threadIdx.x;
    int lane = tid & 63, wv = tid >> 6;
    int wm = (wv >> 1) * 64, wn = (wv & 1) * 64;
    int lr = lane & 15, lg = lane >> 4;
    f32x4 acc[4][4] = {};
    const unsigned short* Bb = h + (size_t)b * S_ * C_;

    for (int k0 = 0; k0 < 256; k0 += 64) {
        __syncthreads();
        #pragma unroll
        for (int i = 0; i < 4; i++) {
            int id = tid + i * 256;
            int row = id >> 3, ck = id & 7;
            u32x4 v = *(const u32x4*)(W + (size_t)(m0 + row) * C_ + k0 + ck * 8);
            unsigned byte = row * 128u + ck * 16u;
            byte ^= ((row & 7u) << 4);
            *(u32x4*)((char*)Alds + byte) = v;
        }
        #pragma unroll
        for (int i = 0; i < 4; i++) {
            int id = tid + i * 256;
            int row = id >> 3, ck = id & 7;
            u32x4 v = *(const u32x4*)(Bb + (size_t)(n0 + row) * C_ + k0 + ck * 8);
            unsigned byte = row * 128u + ck * 16u;
            byte ^= ((row & 7u) << 4);
            *(u32x4*)((char*)Blds + byte) = v;
        }
        __syncthreads();
        #pragma unroll
        for (int ks = 0; ks < 2; ks++) {
            bf16x8 af[4], bf[4];
            #pragma unroll
            for (int mf = 0; mf < 4; mf++) {
                int m = wm + mf * 16 + lr;
                unsigned byte = m * 128u + ks * 64u + lg * 16u;
                byte ^= ((m & 7u) << 4);
                af[mf] = *(bf16x8*)((char*)Alds + byte);
            }
            #pragma unroll
            for (int nf = 0; nf < 4; nf++) {
                int n = wn + nf * 16 + lr;
                unsigned byte = n * 128u + ks * 64u + lg * 16u;
                byte ^= ((n & 7u) << 4);
                bf[nf] = *(bf16x8*)((char*)Blds + byte);
            }
            #pragma unroll
            for (int mf = 0; mf < 4; mf++)
                #pragma unroll
                for (int nf = 0; nf < 4; nf++)
                    acc[mf][nf] = __builtin_amdgcn_mfma_f32_16x16x32_bf16(af[mf], bf[nf], acc[mf][nf], 0, 0, 0);
        }
    }

    if (mode < 2) {
        unsigned char* ob = (mode == 0 ? q8 : k8) + (size_t)b * S_ * C_;
        #pragma unroll
        for (int mf = 0; mf < 4; mf++)
            #pragma unroll
            for (int nf = 0; nf < 4; nf++) {
                int cbase = m0 + wm + mf * 16 + lg * 4;
                int srow = n0 + wn + nf * 16 + lr;
                float v0 = acc[mf][nf][0] + bias[cbase + 0];
                float v1 = acc[mf][nf][1] + bias[cbase + 1];
                float v2 = acc[mf][nf][2] + bias[cbase + 2];
                float v3 = acc[mf][nf][3] + bias[cbase + 3];
                unsigned lo = cvt_pk_fp8(v0, v1);
                unsigned hi = cvt_pk_fp8(v2, v3);
                *(unsigned*)(ob + (size_t)srow * C_ + cbase) = (lo & 0xffffu) | (hi << 16);
            }
    } else {
        unsigned char* ob = v8 + (size_t)b * C_ * S_;
        #pragma unroll
        for (int mf = 0; mf < 4; mf++)
            #pragma unroll
            for (int nf = 0; nf < 4; nf++)
                #pragma unroll
                for (int r = 0; r < 4; r++) {
                    int c = m0 + wm + mf * 16 + lg * 4 + r;
                    int s = n0 + wn + nf * 16 + lr;
                    ob[(size_t)c * S_ + s] = (unsigned char)(cvt_pk_fp8(acc[mf][nf][r] + bias[c], 0.f) & 0xffu);
                }
    }
}

// ---------------- Proj GEMM: fp32 out [C][S] + bias + x residual ----------------
__global__ __launch_bounds__(256) void k_proj(const unsigned short* __restrict__ wbf,
                                              const float* __restrict__ bias,
                                              const unsigned short* __restrict__ Bm,
                                              float* __restrict__ outf,
                                              const float* __restrict__ xres) {
    int b = blockIdx.x & 7;
    int rest = blockIdx.x >> 3;
    int m0 = (rest & 1) * 128;
    int n0 = (rest >> 1) * 128;
    const unsigned short* W = wbf + 3 * 65536;

    __shared__ unsigned short Alds[128 * 64];
    __shared__ unsigned short Blds[128 * 64];
    int tid = threadIdx.x;
    int lane = tid & 63, wv = tid >> 6;
    int wm = (wv >> 1) * 64, wn = (wv & 1) * 64;
    int lr = lane & 15, lg = lane >> 4;
    f32x4 acc[4][4] = {};
    const unsigned short* Bb = Bm + (size_t)b * S_ * C_;

    for (int k0 = 0; k0 < 256; k0 += 64) {
        __syncthreads();
        #pragma unroll
        for (int i = 0; i < 4; i++) {
            int id = tid + i * 256;
            int row = id >> 3, ck = id & 7;
            u32x4 v = *(const u32x4*)(W + (size_t)(m0 + row) * C_ + k0 + ck * 8);
            unsigned byte = row * 128u + ck * 16u;
            byte ^= ((row & 7u) << 4);
            *(u32x4*)((char*)Alds + byte) = v;
        }
        #pragma unroll
        for (int i = 0; i < 4; i++) {
            int id = tid + i * 256;
            int row = id >> 3, ck = id & 7;
            u32x4 v = *(const u32x4*)(Bb + (size_t)(n0 + row) * C_ + k0 + ck * 8);
            unsigned byte = row * 128u + ck * 16u;
            byte ^= ((row & 7u) << 4);
            *(u32x4*)((char*)Blds + byte) = v;
        }
        __syncthreads();
        #pragma unroll
        for (int ks = 0; ks < 2; ks++) {
            bf16x8 af[4], bf[4];
            #pragma unroll
            for (int mf = 0; mf < 4; mf++) {
                int m = wm + mf * 16 + lr;
                unsigned byte = m * 128u + ks * 64u + lg * 16u;
                byte ^= ((m & 7u) << 4);
                af[mf] = *(bf16x8*)((char*)Alds + byte);
            }
            #pragma unroll
            for (int nf = 0; nf < 4; nf++) {
                int n = wn + nf * 16 + lr;
                unsigned byte = n * 128u + ks * 64u + lg * 16u;
                byte ^= ((n & 7u) << 4);
                bf[nf] = *(bf16x8*)((char*)Blds + byte);
            }
            #pragma unroll
            for (int mf = 0; mf < 4; mf++)
                #pragma unroll
                for (int nf = 0; nf < 4; nf++)
                    acc[mf][nf] = __builtin_amdgcn_mfma_f32_16x16x32_bf16(af[mf], bf[nf], acc[mf][nf], 0, 0, 0);
        }
    }

    const float* xb = xres + (size_t)b * C_ * S_;
    #pragma unroll
    for (int mf = 0; mf < 4; mf++)
        #pragma unroll
        for (int nf = 0; nf < 4; nf++)
            #pragma unroll
            for (int r = 0; r < 4; r++) {
                int c = m0 + wm + mf * 16 + lg * 4 + r;
                int s = n0 + wn + nf * 16 + lr;
                outf[(size_t)b * C_ * S_ + (size_t)c * S_ + s] =
                    acc[mf][nf][r] + bias[c] + xb[(size_t)c * S_ + s];
            }
}

// ---------------- Flash attention v17: R15 structure, KVBLK 64 -> 128 ----------------
// Same 2-barrier schedule, 32 tiles of 128 keys (fixed per-tile costs amortized 2x).
// 8 waves: qg = wv&3 (32 q each), kg = wv>>2 (64 keys of each 128-key tile).
// K LDS: 128 rows x 256B, rotated 8B slots; kf offset = +4096B (rotation invariant:
// key+16 -> +32 = 0 mod 32). V rows 136B pad (17 slots, odd -> 17*lr distinct mod 32).
// P rows 136B. PV channel-split: kg owns 128 channels over all 128 keys.
__global__ __launch_bounds__(512, 2) void k_attn(const unsigned char* __restrict__ Q8,  // [B][S][C] fp8
                                                 const unsigned char* __restrict__ K8,  // [B][S][C] fp8
                                                 const unsigned char* __restrict__ V8,  // [B][C][S] fp8
                                                 unsigned short* __restrict__ O) {      // [B][S][C] bf16
    int b = blockIdx.x & 7;
    int q0 = (blockIdx.x >> 3) * 128;
    int tid = threadIdx.x, lane = tid & 63, wv = tid >> 6;  // 8 waves
    int lr = lane & 15, lg = lane >> 4;
    int qg = wv & 3, kg = wv >> 2;
    int qw = q0 + qg * 32;
    __shared__ unsigned char Klds8[128 * 256];    // 32 KB, rotated 8B slots
    __shared__ unsigned char Vlds8[256 * 136];    // 34 KB, [c][128key] rows 136B
    __shared__ unsigned char Plds8[4][32 * 136];  // 17 KB, per-qg [q][128key] rows 136B
    __shared__ float mlp[8 * 2 * 16];
    const unsigned char* Qb = Q8 + (size_t)b * S_ * C_;
    const unsigned char* Kb = K8 + (size_t)b * S_ * C_;
    const unsigned char* Vb = V8 + (size_t)b * C_ * S_;

    const float QS = 0.09016844f;  // C^-0.5 * log2(e)

    // Q fragments fp8
    u32x2 qf8[8][2];
    #pragma unroll
    for (int ks = 0; ks < 8; ks++)
        #pragma unroll
        for (int qf = 0; qf < 2; qf++)
            qf8[ks][qf] = *(const u32x2*)(Qb + (size_t)(qw + qf * 16 + lr) * C_ + ks * 32 + lg * 8);

    // loop-invariant K read addresses for kf=0 (key = kg*64 + lr); kf adds 16 keys = +4096B
    unsigned kaddr[8];
    {
        int key = kg * 64 + lr;
        #pragma unroll
        for (int ks = 0; ks < 8; ks++)
            kaddr[ks] = (unsigned)key * 256u + (((unsigned)(4 * ks + lg + 2 * key) & 31u) << 3);
    }
    // V read base: c = kg*128 + lr; addr = c*136 + lg*8 ; +cf*2176, +ks2*32 compile-time
    unsigned vb0 = (unsigned)(kg * 128 + lr) * 136u + lg * 8u;
    // P read bases per qf: q = qf*16+lr; addr = q*136 + lg*8 ; +ks2*32
    unsigned pb0[2];
    pb0[0] = (unsigned)lr * 136u + lg * 8u;
    pb0[1] = pb0[0] + 16u * 136u;

    f32x4 acc[8][2] = {};
    float lrun[2] = {0.f, 0.f};

    // staging: K 4096 16B-chunks (4/thread); V 4096 8B-chunks (8/thread)
    int kr0[4], kc16[4], vc[8], vk8[8];
    #pragma unroll
    for (int i = 0; i < 4; i++) {
        int id = tid + i * 512;
        kr0[i] = id >> 4; kc16[i] = id & 15;
    }
    #pragma unroll
    for (int i = 0; i < 8; i++) {
        int id = tid + i * 512;
        vc[i] = id >> 4;  vk8[i] = id & 15;
    }
    unsigned kwb[4], vwb[8];
    #pragma unroll
    for (int i = 0; i < 4; i++)
        kwb[i] = kr0[i] * 256u + (((unsigned)(2 * kc16[i] + 2 * kr0[i]) & 31u) << 3);
    #pragma unroll
    for (int i = 0; i < 8; i++)
        vwb[i] = vc[i] * 136u + vk8[i] * 8u;

    u32x4 kpre[4];
    u32x2 vpre[8];
    #pragma unroll
    for (int i = 0; i < 4; i++)
        kpre[i] = *(const u32x4*)(Kb + (size_t)kr0[i] * C_ + kc16[i] * 16);
    #pragma unroll
    for (int i = 0; i < 8; i++)
        vpre[i] = *(const u32x2*)(Vb + (size_t)vc[i] * S_ + vk8[i] * 8);
    #pragma unroll
    for (int i = 0; i < 4; i++)
        *(u32x4*)(Klds8 + kwb[i]) = kpre[i];
    #pragma unroll
    for (int i = 0; i < 8; i++)
        *(u32x2*)(Vlds8 + vwb[i]) = vpre[i];
    __syncthreads();

    for (int kt = 0; kt < 32; kt++) {
        bool pf = (kt + 1) < 32;
        if (pf) {
            const unsigned char* Ks = Kb + (size_t)(kt + 1) * 128 * C_;
            #pragma unroll
            for (int i = 0; i < 4; i++)
                kpre[i] = *(const u32x4*)(Ks + (size_t)kr0[i] * C_ + kc16[i] * 16);
        }

        // QK^T fp8 (swapped): sc[kf][qf], key = kg*64 + kf*16 + lg*4 + r
        f32x4 sc[4][2] = {};
        #pragma unroll
        for (int ks = 0; ks < 8; ks++) {
            u32x2 a[4];
            #pragma unroll
            for (int kf = 0; kf < 4; kf++)
                a[kf] = *(const u32x2*)(Klds8 + kaddr[ks] + kf * 4096u);
            #pragma unroll
            for (int kf = 0; kf < 4; kf++)
                #pragma unroll
                for (int qf = 0; qf < 2; qf++)
                    sc[kf][qf] = mfma_fp8(a[kf], qf8[ks][qf], sc[kf][qf]);
        }

        // softmax: p = exp2(s*QS - 2), P packed fp8
        #pragma unroll
        for (int qf = 0; qf < 2; qf++)
            #pragma unroll
            for (int kf = 0; kf < 4; kf++) {
                float p0 = __builtin_amdgcn_exp2f(fmaf(sc[kf][qf][0], QS, -2.f));
                float p1 = __builtin_amdgcn_exp2f(fmaf(sc[kf][qf][1], QS, -2.f));
                float p2 = __builtin_amdgcn_exp2f(fmaf(sc[kf][qf][2], QS, -2.f));
                float p3 = __builtin_amdgcn_exp2f(fmaf(sc[kf][qf][3], QS, -2.f));
                lrun[qf] += (p0 + p1) + (p2 + p3);
                unsigned pk = (cvt_pk_fp8(p0, p1) & 0xffffu) | (cvt_pk_fp8(p2, p3) << 16);
                int q = qf * 16 + lr;
                *(unsigned*)(&Plds8[qg][0] + (unsigned)q * 136u + kg * 64u + kf * 16u + lg * 4u) = pk;
            }

        if (pf) {
            const unsigned char* Vs = Vb + (size_t)(kt + 1) * 128;
            #pragma unroll
            for (int i = 0; i < 8; i++)
                vpre[i] = *(const u32x2*)(Vs + (size_t)vc[i] * S_ + vk8[i] * 8);
        }

        __syncthreads();  // A: P halves visible to partner; all K reads done

        if (pf) {
            #pragma unroll
            for (int i = 0; i < 4; i++)
                *(u32x4*)(Klds8 + kwb[i]) = kpre[i];
        }

        // PV fp8: O^T[c = kg*128 + cf*16 + ...][q] += V[c][all 128 keys] * P
        #pragma unroll
        for (int ks2 = 0; ks2 < 4; ks2++) {
            u32x2 pb[2];
            #pragma unroll
            for (int qf = 0; qf < 2; qf++)
                pb[qf] = *(const u32x2*)(&Plds8[qg][0] + pb0[qf] + ks2 * 32u);
            #pragma unroll
            for (int cf = 0; cf < 8; cf++) {
                u32x2 va = *(const u32x2*)(Vlds8 + vb0 + ks2 * 32u + cf * 2176u);
                #pragma unroll
                for (int qf = 0; qf < 2; qf++)
                    acc[cf][qf] = mfma_fp8(va, pb[qf], acc[cf][qf]);
            }
        }

        __syncthreads();  // B: V and P reads done; K republish ordered before next QK^T

        if (pf) {
            #pragma unroll
            for (int i = 0; i < 8; i++)
                *(u32x2*)(Vlds8 + vwb[i]) = vpre[i];
        }
    }

    // ---- epilogue: reduce l over lg, exchange across kg partner, direct O store ----
    float ls[2];
    #pragma unroll
    for (int qf = 0; qf < 2; qf++) {
        float t = lrun[qf];
        t += __shfl_xor(t, 16);
        t += __shfl_xor(t, 32);
        ls[qf] = t;
    }
    if (lg == 0) {
        #pragma unroll
        for (int qf = 0; qf < 2; qf++) mlp[(wv * 2 + qf) * 16 + lr] = ls[qf];
    }
    __syncthreads();
    unsigned short* Ob = O + (size_t)b * S_ * C_;
    #pragma unroll
    for (int qf = 0; qf < 2; qf++) {
        float inv = 1.f / (ls[qf] + mlp[((wv ^ 4) * 2 + qf) * 16 + lr]);
        int srow = qw + qf * 16 + lr;
        #pragma unroll
        for (int cf = 0; cf < 8; cf++) {
            u32x2 pk;
            pk[0] = cvt_pk_bf16(acc[cf][qf][0] * inv, acc[cf][qf][1] * inv);
            pk[1] = cvt_pk_bf16(acc[cf][qf][2] * inv, acc[cf][qf][3] * inv);
            *(u32x2*)(Ob + (size_t)srow * C_ + kg * 128 + cf * 16 + lg * 4) = pk;
        }
    }
}

__global__ __launch_bounds__(256) void k_copy_temb(const float* __restrict__ t, float* __restrict__ o) {
    int i = blockIdx.x * 256 + threadIdx.x;
    if (i < B_ * 512) o[i] = t[i];
}

extern "C" void kernel_launch(void* const* d_in, const int* in_sizes, int n_in,
                              void* d_out, int out_size, void* d_ws, size_t ws_size,
                              hipStream_t stream) {
    (void)in_sizes; (void)n_in; (void)out_size; (void)ws_size;
    const float* x  = (const float*)d_in[0];
    const float* temb = (const float*)d_in[1];
    const float* gw = (const float*)d_in[2];
    const float* gb = (const float*)d_in[3];
    const float* wq = (const float*)d_in[4];
    const float* bq = (const float*)d_in[5];
    const float* wk = (const float*)d_in[6];
    const float* bk = (const float*)d_in[7];
    const float* wv = (const float*)d_in[8];
    const float* bv = (const float*)d_in[9];
    const float* wp = (const float*)d_in[10];
    const float* bp = (const float*)d_in[11];
    float* out = (float*)d_out;

    char* ws = (char*)d_ws;
    const size_t MB = 1024 * 1024;
    unsigned short* h_sc = (unsigned short*)ws;              // [B][S][C] bf16, 16MB; reused for attn out
    unsigned char*  v8   = (unsigned char*)(ws + 16 * MB);   // [B][C][S] fp8, 8MB
    unsigned char*  q8   = (unsigned char*)(ws + 24 * MB);   // [B][S][C] fp8, 8MB
    unsigned char*  k8   = (unsigned char*)(ws + 32 * MB);   // [B][S][C] fp8, 8MB
    float* stats = (float*)(ws + 40 * MB);                   // [B*G][2]
    unsigned short* wbf = (unsigned short*)(ws + 40 * MB + 4096);  // [4][256][256] bf16

    k_wcvt<<<128, 256, 0, stream>>>(wq, wk, wv, wp, wbf);
    k_gn_stats<<<B_ * G_, 256, 0, stream>>>(x, stats);
    k_gn_apply<<<B_ * (S_ / 64), 256, 0, stream>>>(x, stats, gw, gb, h_sc);
    k_qkv<<<1536, 256, 0, stream>>>(wbf, bq, bk, bv, h_sc, q8, k8, v8);
    k_attn<<<B_ * (S_ / 128), 512, 0, stream>>>(q8, k8, v8, h_sc);
    k_proj<<<512, 256, 0, stream>>>(wbf, bp, h_sc, out, x);
    k_copy_temb<<<(B_ * 512 + 255) / 256, 256, 0, stream>>>(temb, out + (size_t)B_ * C_ * S_);
}

// Round 20
// 193.310 us; speedup vs baseline: 1.3817x; 1.3817x over previous
//
#include <hip/hip_runtime.h>
#include <hip/hip_bf16.h>

#define B_ 8
#define C_ 256
#define S_ 4096
#define G_ 32
#define GC_ 8
#define EPS_ 1e-5f

typedef __attribute__((ext_vector_type(4))) float f32x4;
typedef __attribute__((ext_vector_type(8))) short bf16x8;
typedef __attribute__((ext_vector_type(4))) short bf16x4;
typedef __attribute__((ext_vector_type(4))) unsigned int u32x4;
typedef __attribute__((ext_vector_type(2))) unsigned int u32x2;

#define DI __device__ __forceinline__

DI unsigned short f2bf(float f) {
    union { float f; unsigned u; } v; v.f = f;
    unsigned r = v.u + 0x7fffu + ((v.u >> 16) & 1u);
    return (unsigned short)(r >> 16);
}

DI unsigned cvt_pk_bf16(float lo, float hi) {
    unsigned r;
    asm("v_cvt_pk_bf16_f32 %0, %1, %2" : "=v"(r) : "v"(lo), "v"(hi));
    return r;
}

DI unsigned cvt_pk_fp8(float lo, float hi) {  // bits [7:0]=fp8(lo), [15:8]=fp8(hi)
    unsigned r;
    asm("v_cvt_pk_fp8_f32 %0, %1, %2" : "=v"(r) : "v"(lo), "v"(hi));
    return r;
}

DI f32x4 mfma_fp8(u32x2 a, u32x2 b, f32x4 c) {
    union { u32x2 u; long l; } ua, ub;
    ua.u = a; ub.u = b;
    return __builtin_amdgcn_mfma_f32_16x16x32_fp8_fp8(ua.l, ub.l, c, 0, 0, 0);
}

// ---------------- GroupNorm stats: one block per (b, group) ----------------
__global__ __launch_bounds__(256) void k_gn_stats(const float* __restrict__ x,
                                                  float* __restrict__ stats) {
    int bg = blockIdx.x;
    const float4* xp = (const float4*)(x + (size_t)bg * (GC_ * S_));
    float s = 0.f, ss = 0.f;
    for (int i = threadIdx.x; i < GC_ * S_ / 4; i += 256) {
        float4 v = xp[i];
        s  += v.x + v.y + v.z + v.w;
        ss += v.x * v.x + v.y * v.y + v.z * v.z + v.w * v.w;
    }
    #pragma unroll
    for (int off = 32; off; off >>= 1) { s += __shfl_down(s, off); ss += __shfl_down(ss, off); }
    __shared__ float rs[4], rss[4];
    int w = threadIdx.x >> 6;
    if ((threadIdx.x & 63) == 0) { rs[w] = s; rss[w] = ss; }
    __syncthreads();
    if (threadIdx.x == 0) {
        float S1 = rs[0] + rs[1] + rs[2] + rs[3];
        float S2 = rss[0] + rss[1] + rss[2] + rss[3];
        float inv = 1.f / (GC_ * S_);
        float mean = S1 * inv;
        float var = S2 * inv - mean * mean;
        stats[bg * 2] = mean;
        stats[bg * 2 + 1] = rsqrtf(var + EPS_);
    }
}

// ------------- GN apply + transpose: x[B][C][S] -> h_sc[B][S][C] bf16 -------------
__global__ __launch_bounds__(256) void k_gn_apply(const float* __restrict__ x,
                                                  const float* __restrict__ stats,
                                                  const float* __restrict__ gw,
                                                  const float* __restrict__ gb,
                                                  unsigned short* __restrict__ h) {
    int b = blockIdx.x >> 6;
    int s0 = (blockIdx.x & 63) * 64;
    __shared__ unsigned short tile[64 * 256];
    const float* xb = x + (size_t)b * C_ * S_;
    for (int id = threadIdx.x; id < 256 * 16; id += 256) {
        int c = id >> 4, s4 = id & 15;
        float4 v = *(const float4*)(xb + (size_t)c * S_ + s0 + s4 * 4);
        float mean = stats[(b * G_ + (c >> 3)) * 2];
        float rstd = stats[(b * G_ + (c >> 3)) * 2 + 1];
        float ga = gw[c], be = gb[c];
        float vv[4] = {v.x, v.y, v.z, v.w};
        #pragma unroll
        for (int i = 0; i < 4; i++) {
            int srow = s4 * 4 + i;
            unsigned byte = srow * 512u + c * 2u;
            byte ^= ((srow & 7u) << 4);
            *(unsigned short*)((char*)tile + byte) = f2bf((vv[i] - mean) * rstd * ga + be);
        }
    }
    __syncthreads();
    unsigned short* hb = h + (size_t)b * S_ * C_;
    for (int id = threadIdx.x; id < 2048; id += 256) {
        int srow = id >> 5, ck = id & 31;
        unsigned byte = srow * 512u + ck * 16u;
        byte ^= ((srow & 7u) << 4);
        u32x4 v = *(u32x4*)((char*)tile + byte);
        *(u32x4*)(hb + (size_t)(s0 + srow) * C_ + ck * 8) = v;
    }
}

// ---------------- W fp32 -> bf16 pre-pass ----------------
__global__ __launch_bounds__(256) void k_wcvt(const float* __restrict__ wq, const float* __restrict__ wk,
                                              const float* __restrict__ wv, const float* __restrict__ wp,
                                              unsigned short* __restrict__ wbf) {
    int t = blockIdx.x * 256 + threadIdx.x;
    int mat = t >> 13;
    int idx = (t & 8191) * 8;
    const float* src = mat == 0 ? wq : mat == 1 ? wk : mat == 2 ? wv : wp;
    float4 a = *(const float4*)(src + idx);
    float4 c = *(const float4*)(src + idx + 4);
    unsigned short tmp[8] = {f2bf(a.x), f2bf(a.y), f2bf(a.z), f2bf(a.w),
                             f2bf(c.x), f2bf(c.y), f2bf(c.z), f2bf(c.w)};
    *(u32x4*)(wbf + mat * 65536 + idx) = *(u32x4*)tmp;
}

// ---------------- Fused QKV GEMM: Q,K -> fp8 [S][C]; V -> fp8 [C][S] ----------------
__global__ __launch_bounds__(256) void k_qkv(const unsigned short* __restrict__ wbf,
                                             const float* __restrict__ bq,
                                             const float* __restrict__ bk,
                                             const float* __restrict__ bv,
                                             const unsigned short* __restrict__ h,
                                             unsigned char* __restrict__ q8,
                                             unsigned char* __restrict__ k8,
                                             unsigned char* __restrict__ v8) {
    int mode = blockIdx.x >> 9;
    int inner = blockIdx.x & 511;
    int b = inner & 7;
    int rest = inner >> 3;
    int m0 = (rest & 1) * 128;
    int n0 = (rest >> 1) * 128;
    const unsigned short* W = wbf + mode * 65536;
    const float* bias = mode == 0 ? bq : (mode == 1 ? bk : bv);

    __shared__ unsigned short Alds[128 * 64];
    __shared__ unsigned short Blds[128 * 64];
    int tid = threadIdx.x;
    int lane = tid & 63, wv = tid >> 6;
    int wm = (wv >> 1) * 64, wn = (wv & 1) * 64;
    int lr = lane & 15, lg = lane >> 4;
    f32x4 acc[4][4] = {};
    const unsigned short* Bb = h + (size_t)b * S_ * C_;

    for (int k0 = 0; k0 < 256; k0 += 64) {
        __syncthreads();
        #pragma unroll
        for (int i = 0; i < 4; i++) {
            int id = tid + i * 256;
            int row = id >> 3, ck = id & 7;
            u32x4 v = *(const u32x4*)(W + (size_t)(m0 + row) * C_ + k0 + ck * 8);
            unsigned byte = row * 128u + ck * 16u;
            byte ^= ((row & 7u) << 4);
            *(u32x4*)((char*)Alds + byte) = v;
        }
        #pragma unroll
        for (int i = 0; i < 4; i++) {
            int id = tid + i * 256;
            int row = id >> 3, ck = id & 7;
            u32x4 v = *(const u32x4*)(Bb + (size_t)(n0 + row) * C_ + k0 + ck * 8);
            unsigned byte = row * 128u + ck * 16u;
            byte ^= ((row & 7u) << 4);
            *(u32x4*)((char*)Blds + byte) = v;
        }
        __syncthreads();
        #pragma unroll
        for (int ks = 0; ks < 2; ks++) {
            bf16x8 af[4], bf[4];
            #pragma unroll
            for (int mf = 0; mf < 4; mf++) {
                int m = wm + mf * 16 + lr;
                unsigned byte = m * 128u + ks * 64u + lg * 16u;
                byte ^= ((m & 7u) << 4);
                af[mf] = *(bf16x8*)((char*)Alds + byte);
            }
            #pragma unroll
            for (int nf = 0; nf < 4; nf++) {
                int n = wn + nf * 16 + lr;
                unsigned byte = n * 128u + ks * 64u + lg * 16u;
                byte ^= ((n & 7u) << 4);
                bf[nf] = *(bf16x8*)((char*)Blds + byte);
            }
            #pragma unroll
            for (int mf = 0; mf < 4; mf++)
                #pragma unroll
                for (int nf = 0; nf < 4; nf++)
                    acc[mf][nf] = __builtin_amdgcn_mfma_f32_16x16x32_bf16(af[mf], bf[nf], acc[mf][nf], 0, 0, 0);
        }
    }

    if (mode < 2) {
        unsigned char* ob = (mode == 0 ? q8 : k8) + (size_t)b * S_ * C_;
        #pragma unroll
        for (int mf = 0; mf < 4; mf++)
            #pragma unroll
            for (int nf = 0; nf < 4; nf++) {
                int cbase = m0 + wm + mf * 16 + lg * 4;
                int srow = n0 + wn + nf * 16 + lr;
                float v0 = acc[mf][nf][0] + bias[cbase + 0];
                float v1 = acc[mf][nf][1] + bias[cbase + 1];
                float v2 = acc[mf][nf][2] + bias[cbase + 2];
                float v3 = acc[mf][nf][3] + bias[cbase + 3];
                unsigned lo = cvt_pk_fp8(v0, v1);
                unsigned hi = cvt_pk_fp8(v2, v3);
                *(unsigned*)(ob + (size_t)srow * C_ + cbase) = (lo & 0xffffu) | (hi << 16);
            }
    } else {
        unsigned char* ob = v8 + (size_t)b * C_ * S_;
        #pragma unroll
        for (int mf = 0; mf < 4; mf++)
            #pragma unroll
            for (int nf = 0; nf < 4; nf++)
                #pragma unroll
                for (int r = 0; r < 4; r++) {
                    int c = m0 + wm + mf * 16 + lg * 4 + r;
                    int s = n0 + wn + nf * 16 + lr;
                    ob[(size_t)c * S_ + s] = (unsigned char)(cvt_pk_fp8(acc[mf][nf][r] + bias[c], 0.f) & 0xffu);
                }
    }
}

// ---------------- Proj GEMM: fp32 out [C][S] + bias + x residual ----------------
__global__ __launch_bounds__(256) void k_proj(const unsigned short* __restrict__ wbf,
                                              const float* __restrict__ bias,
                                              const unsigned short* __restrict__ Bm,
                                              float* __restrict__ outf,
                                              const float* __restrict__ xres) {
    int b = blockIdx.x & 7;
    int rest = blockIdx.x >> 3;
    int m0 = (rest & 1) * 128;
    int n0 = (rest >> 1) * 128;
    const unsigned short* W = wbf + 3 * 65536;

    __shared__ unsigned short Alds[128 * 64];
    __shared__ unsigned short Blds[128 * 64];
    int tid = threadIdx.x;
    int lane = tid & 63, wv = tid >> 6;
    int wm = (wv >> 1) * 64, wn = (wv & 1) * 64;
    int lr = lane & 15, lg = lane >> 4;
    f32x4 acc[4][4] = {};
    const unsigned short* Bb = Bm + (size_t)b * S_ * C_;

    for (int k0 = 0; k0 < 256; k0 += 64) {
        __syncthreads();
        #pragma unroll
        for (int i = 0; i < 4; i++) {
            int id = tid + i * 256;
            int row = id >> 3, ck = id & 7;
            u32x4 v = *(const u32x4*)(W + (size_t)(m0 + row) * C_ + k0 + ck * 8);
            unsigned byte = row * 128u + ck * 16u;
            byte ^= ((row & 7u) << 4);
            *(u32x4*)((char*)Alds + byte) = v;
        }
        #pragma unroll
        for (int i = 0; i < 4; i++) {
            int id = tid + i * 256;
            int row = id >> 3, ck = id & 7;
            u32x4 v = *(const u32x4*)(Bb + (size_t)(n0 + row) * C_ + k0 + ck * 8);
            unsigned byte = row * 128u + ck * 16u;
            byte ^= ((row & 7u) << 4);
            *(u32x4*)((char*)Blds + byte) = v;
        }
        __syncthreads();
        #pragma unroll
        for (int ks = 0; ks < 2; ks++) {
            bf16x8 af[4], bf[4];
            #pragma unroll
            for (int mf = 0; mf < 4; mf++) {
                int m = wm + mf * 16 + lr;
                unsigned byte = m * 128u + ks * 64u + lg * 16u;
                byte ^= ((m & 7u) << 4);
                af[mf] = *(bf16x8*)((char*)Alds + byte);
            }
            #pragma unroll
            for (int nf = 0; nf < 4; nf++) {
                int n = wn + nf * 16 + lr;
                unsigned byte = n * 128u + ks * 64u + lg * 16u;
                byte ^= ((n & 7u) << 4);
                bf[nf] = *(bf16x8*)((char*)Blds + byte);
            }
            #pragma unroll
            for (int mf = 0; mf < 4; mf++)
                #pragma unroll
                for (int nf = 0; nf < 4; nf++)
                    acc[mf][nf] = __builtin_amdgcn_mfma_f32_16x16x32_bf16(af[mf], bf[nf], acc[mf][nf], 0, 0, 0);
        }
    }

    const float* xb = xres + (size_t)b * C_ * S_;
    #pragma unroll
    for (int mf = 0; mf < 4; mf++)
        #pragma unroll
        for (int nf = 0; nf < 4; nf++)
            #pragma unroll
            for (int r = 0; r < 4; r++) {
                int c = m0 + wm + mf * 16 + lg * 4 + r;
                int s = n0 + wn + nf * 16 + lr;
                outf[(size_t)b * C_ * S_ + (size_t)c * S_ + s] =
                    acc[mf][nf][r] + bias[c] + xb[(size_t)c * S_ + s];
            }
}

// ---------------- Flash attention (FINAL = R15 best): 128-q blocks, full fp8 LDS ----------------
// 8 waves: qg = wv&3 (32 q each), kg = wv>>2 (32 keys of each 64-key tile).
// QK^T fp8 (rotated K slots, loop-invariant addrs); PV fp8 (V rows 72B pad, P rows 72B);
// p = exp2(s*QS - 2); l f32; channel-split PV (kg owns 128 channels); 2 barriers/tile.
__global__ __launch_bounds__(512, 2) void k_attn(const unsigned char* __restrict__ Q8,  // [B][S][C] fp8
                                                 const unsigned char* __restrict__ K8,  // [B][S][C] fp8
                                                 const unsigned char* __restrict__ V8,  // [B][C][S] fp8
                                                 unsigned short* __restrict__ O) {      // [B][S][C] bf16
    int b = blockIdx.x & 7;
    int q0 = (blockIdx.x >> 3) * 128;
    int tid = threadIdx.x, lane = tid & 63, wv = tid >> 6;  // 8 waves
    int lr = lane & 15, lg = lane >> 4;
    int qg = wv & 3, kg = wv >> 2;
    int qw = q0 + qg * 32;
    __shared__ unsigned char Klds8[64 * 256];    // 16 KB, rotated 8B slots
    __shared__ unsigned char Vlds8[256 * 72];    // 18 KB, [c][64key] rows 72B
    __shared__ unsigned char Plds8[4][32 * 72];  // 9 KB, per-qg [q][64key] rows 72B
    __shared__ float mlp[8 * 2 * 16];
    const unsigned char* Qb = Q8 + (size_t)b * S_ * C_;
    const unsigned char* Kb = K8 + (size_t)b * S_ * C_;
    const unsigned char* Vb = V8 + (size_t)b * C_ * S_;

    const float QS = 0.09016844f;  // C^-0.5 * log2(e)

    // Q fragments fp8
    u32x2 qf8[8][2];
    #pragma unroll
    for (int ks = 0; ks < 8; ks++)
        #pragma unroll
        for (int qf = 0; qf < 2; qf++)
            qf8[ks][qf] = *(const u32x2*)(Qb + (size_t)(qw + qf * 16 + lr) * C_ + ks * 32 + lg * 8);

    // loop-invariant K read addresses (8B-slot rotation)
    unsigned kaddr[2][8];
    #pragma unroll
    for (int kf = 0; kf < 2; kf++) {
        int key = kg * 32 + kf * 16 + lr;
        #pragma unroll
        for (int ks = 0; ks < 8; ks++)
            kaddr[kf][ks] = (unsigned)key * 256u + (((unsigned)(4 * ks + lg + 2 * key) & 31u) << 3);
    }
    // V read bases: c = kg*128 + cf*16 + lr; addr = c*72 + ks2*32 + lg*8 ; cf adds 1152
    unsigned vbase[2];
    vbase[0] = (unsigned)(kg * 128 + lr) * 72u + lg * 8u;
    vbase[1] = vbase[0] + 32u;

    f32x4 acc[8][2] = {};
    float lrun[2] = {0.f, 0.f};

    // staging: K 1024 16B-chunks (2/thread); V 2048 8B-chunks (4/thread)
    int kr0[2], kc16[2], vc[4], vk8[4];
    #pragma unroll
    for (int i = 0; i < 2; i++) {
        int id = tid + i * 512;
        kr0[i] = id >> 4; kc16[i] = id & 15;
    }
    #pragma unroll
    for (int i = 0; i < 4; i++) {
        int id = tid + i * 512;
        vc[i] = id >> 3;  vk8[i] = id & 7;
    }
    unsigned kwb[2], vwb[4];
    #pragma unroll
    for (int i = 0; i < 2; i++)
        kwb[i] = kr0[i] * 256u + (((unsigned)(2 * kc16[i] + 2 * kr0[i]) & 31u) << 3);
    #pragma unroll
    for (int i = 0; i < 4; i++)
        vwb[i] = vc[i] * 72u + vk8[i] * 8u;

    u32x4 kpre[2];
    u32x2 vpre[4];
    #pragma unroll
    for (int i = 0; i < 2; i++)
        kpre[i] = *(const u32x4*)(Kb + (size_t)kr0[i] * C_ + kc16[i] * 16);
    #pragma unroll
    for (int i = 0; i < 4; i++)
        vpre[i] = *(const u32x2*)(Vb + (size_t)vc[i] * S_ + vk8[i] * 8);
    #pragma unroll
    for (int i = 0; i < 2; i++)
        *(u32x4*)(Klds8 + kwb[i]) = kpre[i];
    #pragma unroll
    for (int i = 0; i < 4; i++)
        *(u32x2*)(Vlds8 + vwb[i]) = vpre[i];
    __syncthreads();

    for (int kt = 0; kt < 64; kt++) {
        bool pf = (kt + 1) < 64;
        if (pf) {
            #pragma unroll
            for (int i = 0; i < 2; i++)
                kpre[i] = *(const u32x4*)(Kb + (size_t)((kt + 1) * 64 + kr0[i]) * C_ + kc16[i] * 16);
        }

        // QK^T fp8 (swapped)
        f32x4 sc[2][2] = {};
        #pragma unroll
        for (int ks = 0; ks < 8; ks++) {
            u32x2 a0 = *(const u32x2*)(Klds8 + kaddr[0][ks]);
            u32x2 a1 = *(const u32x2*)(Klds8 + kaddr[1][ks]);
            sc[0][0] = mfma_fp8(a0, qf8[ks][0], sc[0][0]);
            sc[0][1] = mfma_fp8(a0, qf8[ks][1], sc[0][1]);
            sc[1][0] = mfma_fp8(a1, qf8[ks][0], sc[1][0]);
            sc[1][1] = mfma_fp8(a1, qf8[ks][1], sc[1][1]);
        }

        // softmax: p = exp2(s*QS - 2)  (e4m3-friendly range), P packed fp8
        #pragma unroll
        for (int qf = 0; qf < 2; qf++)
            #pragma unroll
            for (int kf = 0; kf < 2; kf++) {
                float p0 = __builtin_amdgcn_exp2f(fmaf(sc[kf][qf][0], QS, -2.f));
                float p1 = __builtin_amdgcn_exp2f(fmaf(sc[kf][qf][1], QS, -2.f));
                float p2 = __builtin_amdgcn_exp2f(fmaf(sc[kf][qf][2], QS, -2.f));
                float p3 = __builtin_amdgcn_exp2f(fmaf(sc[kf][qf][3], QS, -2.f));
                lrun[qf] += (p0 + p1) + (p2 + p3);
                unsigned pk = (cvt_pk_fp8(p0, p1) & 0xffffu) | (cvt_pk_fp8(p2, p3) << 16);
                int q = qf * 16 + lr;
                *(unsigned*)(&Plds8[qg][0] + (unsigned)q * 72u + kg * 32u + kf * 16u + lg * 4u) = pk;
            }

        if (pf) {
            #pragma unroll
            for (int i = 0; i < 4; i++)
                vpre[i] = *(const u32x2*)(Vb + (size_t)vc[i] * S_ + (kt + 1) * 64 + vk8[i] * 8);
        }

        __syncthreads();  // A: P halves visible to partner; all K reads done

        if (pf) {
            #pragma unroll
            for (int i = 0; i < 2; i++)
                *(u32x4*)(Klds8 + kwb[i]) = kpre[i];
        }

        // PV fp8: O^T[c = kg*128 + cf*16 + ...][q] += V[c][all 64 keys] * P
        #pragma unroll
        for (int ks2 = 0; ks2 < 2; ks2++) {
            u32x2 pb[2];
            #pragma unroll
            for (int qf = 0; qf < 2; qf++) {
                int q = qf * 16 + lr;
                pb[qf] = *(const u32x2*)(&Plds8[qg][0] + (unsigned)q * 72u + ks2 * 32u + lg * 8u);
            }
            #pragma unroll
            for (int cf = 0; cf < 8; cf++) {
                u32x2 va = *(const u32x2*)(Vlds8 + vbase[ks2] + cf * 1152u);
                #pragma unroll
                for (int qf = 0; qf < 2; qf++)
                    acc[cf][qf] = mfma_fp8(va, pb[qf], acc[cf][qf]);
            }
        }

        __syncthreads();  // B: V and P reads done; K republish ordered before next QK^T

        if (pf) {
            #pragma unroll
            for (int i = 0; i < 4; i++)
                *(u32x2*)(Vlds8 + vwb[i]) = vpre[i];
        }
    }

    // ---- epilogue: reduce l over lg, exchange across kg partner, direct O store ----
    float ls[2];
    #pragma unroll
    for (int qf = 0; qf < 2; qf++) {
        float t = lrun[qf];
        t += __shfl_xor(t, 16);
        t += __shfl_xor(t, 32);
        ls[qf] = t;
    }
    if (lg == 0) {
        #pragma unroll
        for (int qf = 0; qf < 2; qf++) mlp[(wv * 2 + qf) * 16 + lr] = ls[qf];
    }
    __syncthreads();
    unsigned short* Ob = O + (size_t)b * S_ * C_;
    #pragma unroll
    for (int qf = 0; qf < 2; qf++) {
        float inv = 1.f / (ls[qf] + mlp[((wv ^ 4) * 2 + qf) * 16 + lr]);
        int srow = qw + qf * 16 + lr;
        #pragma unroll
        for (int cf = 0; cf < 8; cf++) {
            u32x2 pk;
            pk[0] = cvt_pk_bf16(acc[cf][qf][0] * inv, acc[cf][qf][1] * inv);
            pk[1] = cvt_pk_bf16(acc[cf][qf][2] * inv, acc[cf][qf][3] * inv);
            *(u32x2*)(Ob + (size_t)srow * C_ + kg * 128 + cf * 16 + lg * 4) = pk;
        }
    }
}

__global__ __launch_bounds__(256) void k_copy_temb(const float* __restrict__ t, float* __restrict__ o) {
    int i = blockIdx.x * 256 + threadIdx.x;
    if (i < B_ * 512) o[i] = t[i];
}

extern "C" void kernel_launch(void* const* d_in, const int* in_sizes, int n_in,
                              void* d_out, int out_size, void* d_ws, size_t ws_size,
                              hipStream_t stream) {
    (void)in_sizes; (void)n_in; (void)out_size; (void)ws_size;
    const float* x  = (const float*)d_in[0];
    const float* temb = (const float*)d_in[1];
    const float* gw = (const float*)d_in[2];
    const float* gb = (const float*)d_in[3];
    const float* wq = (const float*)d_in[4];
    const float* bq = (const float*)d_in[5];
    const float* wk = (const float*)d_in[6];
    const float* bk = (const float*)d_in[7];
    const float* wv = (const float*)d_in[8];
    const float* bv = (const float*)d_in[9];
    const float* wp = (const float*)d_in[10];
    const float* bp = (const float*)d_in[11];
    float* out = (float*)d_out;

    char* ws = (char*)d_ws;
    const size_t MB = 1024 * 1024;
    unsigned short* h_sc = (unsigned short*)ws;              // [B][S][C] bf16, 16MB; reused for attn out
    unsigned char*  v8   = (unsigned char*)(ws + 16 * MB);   // [B][C][S] fp8, 8MB
    unsigned char*  q8   = (unsigned char*)(ws + 24 * MB);   // [B][S][C] fp8, 8MB
    unsigned char*  k8   = (unsigned char*)(ws + 32 * MB);   // [B][S][C] fp8, 8MB
    float* stats = (float*)(ws + 40 * MB);                   // [B*G][2]
    unsigned short* wbf = (unsigned short*)(ws + 40 * MB + 4096);  // [4][256][256] bf16

    k_wcvt<<<128, 256, 0, stream>>>(wq, wk, wv, wp, wbf);
    k_gn_stats<<<B_ * G_, 256, 0, stream>>>(x, stats);
    k_gn_apply<<<B_ * (S_ / 64), 256, 0, stream>>>(x, stats, gw, gb, h_sc);
    k_qkv<<<1536, 256, 0, stream>>>(wbf, bq, bk, bv, h_sc, q8, k8, v8);
    k_attn<<<B_ * (S_ / 128), 512, 0, stream>>>(q8, k8, v8, h_sc);
    k_proj<<<512, 256, 0, stream>>>(wbf, bp, h_sc, out, x);
    k_copy_temb<<<(B_ * 512 + 255) / 256, 256, 0, stream>>>(temb, out + (size_t)B_ * C_ * S_);
}